// Round 8
// baseline (510.302 us; speedup 1.0000x reference)
//
#include <hip/hip_runtime.h>
#include <hip/hip_bf16.h>

#define NB_B 16
#define NH 16
#define NBLK 32
#define BSZ 128
#define DH 64
#define DM 1024
#define KVLEN 4096
#define NCH 16
#define CHUNK 256

// ws layout (floats):
// 0                  : q      (B*DM)
// B*DM               : k_new  (B*DM)
// 2*B*DM             : v_new  (B*DM)
// 3*B*DM             : part_m (B*H*NCH)
// +B*H*NCH           : part_l (B*H*NCH)
// +B*H*NCH           : part_ctx (B*H*NCH*DH)
// +B*H*NCH*DH        : ctx    (B*DM)
// +B*DM              : done-counters (B*H ints)

// One 32-lane group per weight row; full row (8 float4/lane) in registers;
// loop over all 16 batches staged in LDS. Weights stream from HBM once.
// Block 0 also zeroes the per-(b,h) done counters for the attn kernel
// (visible to attn via stream order).
__global__ __launch_bounds__(256) void qkv_all(
    const float* __restrict__ hs,
    const float* __restrict__ Wq, const float* __restrict__ bq,
    const float* __restrict__ Wk, const float* __restrict__ bk,
    const float* __restrict__ Wv, const float* __restrict__ bv,
    float* __restrict__ ws, int* __restrict__ cnt)
{
    if (blockIdx.x == 0) cnt[threadIdx.x] = 0;   // 256 == NB_B*NH

    __shared__ float sh[NB_B][DM];          // 64 KB: all batches' hidden states
    int tid = threadIdx.x;
#pragma unroll
    for (int i = 0; i < 16; ++i) {
        int idx = i * 256 + tid;            // float4 index, 4096 total
        ((float4*)sh)[idx] = ((const float4*)hs)[idx];
    }
    __syncthreads();

    int grp = tid >> 5, gl = tid & 31;      // 8 groups of 32 lanes
    int row = blockIdx.x * 8 + grp;         // 0 .. 3*DM-1
    int m = row >> 10;                      // 0=q,1=k,2=v
    int o = row & (DM - 1);
    const float* W    = (m == 0) ? Wq : (m == 1) ? Wk : Wv;
    const float* bias = (m == 0) ? bq : (m == 1) ? bk : bv;
    const float4* wrow = (const float4*)(W + (size_t)o * DM);
    float4 w[8];
#pragma unroll
    for (int k = 0; k < 8; ++k) w[k] = wrow[gl + 32 * k];
    float bb = bias[o];

    for (int b = 0; b < NB_B; ++b) {
        const float4* x = (const float4*)sh[b];
        float acc = 0.f;
#pragma unroll
        for (int k = 0; k < 8; ++k) {
            float4 xv = x[gl + 32 * k];
            acc += w[k].x * xv.x + w[k].y * xv.y + w[k].z * xv.z + w[k].w * xv.w;
        }
        acc += __shfl_xor(acc, 1);
        acc += __shfl_xor(acc, 2);
        acc += __shfl_xor(acc, 4);
        acc += __shfl_xor(acc, 8);
        acc += __shfl_xor(acc, 16);
        if (gl == 0)
            ws[(size_t)m * (NB_B * DM) + (size_t)b * DM + o] = acc + bb;
    }
}

__global__ __launch_bounds__(128) void out_all(
    const float* __restrict__ ctx, const float* __restrict__ Wo,
    const float* __restrict__ bo, float* __restrict__ out)
{
    __shared__ float sh[NB_B][DM];          // 64 KB: all batches' context
    int tid = threadIdx.x;
#pragma unroll
    for (int i = 0; i < 32; ++i) {
        int idx = i * 128 + tid;
        ((float4*)sh)[idx] = ((const float4*)ctx)[idx];
    }
    __syncthreads();

    int grp = tid >> 5, gl = tid & 31;      // 4 groups of 32 lanes
    int o = blockIdx.x * 4 + grp;           // 0 .. DM-1
    const float4* wrow = (const float4*)(Wo + (size_t)o * DM);
    float4 w[8];
#pragma unroll
    for (int k = 0; k < 8; ++k) w[k] = wrow[gl + 32 * k];
    float bb = bo[o];

    for (int b = 0; b < NB_B; ++b) {
        const float4* x = (const float4*)sh[b];
        float acc = 0.f;
#pragma unroll
        for (int k = 0; k < 8; ++k) {
            float4 xv = x[gl + 32 * k];
            acc += w[k].x * xv.x + w[k].y * xv.y + w[k].z * xv.z + w[k].w * xv.w;
        }
        acc += __shfl_xor(acc, 1);
        acc += __shfl_xor(acc, 2);
        acc += __shfl_xor(acc, 4);
        acc += __shfl_xor(acc, 8);
        acc += __shfl_xor(acc, 16);
        if (gl == 0)
            out[(size_t)b * DM + o] = acc + bb;
    }
}

// 8-lane groups: each lane owns 8 contiguous floats of K/V; wave covers
// 8 positions per iteration. XCD-aware swizzle keeps all 16 chunks of one
// (b,h) on the same XCD (duplicate physical blocks hit that XCD's L2).
// Last finishing chunk of each (b,h) performs the cross-chunk softmax
// reduce (rocPRIM-style threadfence + atomic counter), removing the
// separate attn_reduce kernel.
__global__ __launch_bounds__(256) void attn_partial(
    const float* __restrict__ kc, const float* __restrict__ vc,
    const float* __restrict__ mask,
    const int* __restrict__ cpos, const int* __restrict__ bt,
    const float* __restrict__ wsin,   // q, k_new, v_new
    float* __restrict__ pm, float* __restrict__ pl, float* __restrict__ pctx,
    float* __restrict__ ctx_out, int* __restrict__ cnt)
{
    // 4096 = 8 XCDs * 512; XCD x owns sw in [512x, 512x+512) = 2 full batches
    int id = blockIdx.x;
    int sw = (id & 7) * 512 + (id >> 3);
    int c = sw & (NCH - 1);
    int h = (sw >> 4) & (NH - 1);
    int b = sw >> 8;

    int tid = threadIdx.x;
    int wave = tid >> 6, lane = tid & 63;
    int g = lane >> 3, gl = lane & 7;       // 8 groups of 8 lanes per wave

    int pos = cpos[b];
    int nvalid = pos + 1;
    int start = c * CHUNK;
    if (start >= nvalid) return;            // empty chunk, uniform exit
    int end = min(start + CHUNK, nvalid);
    int bh = b * NH + h;
    int nch_b = (nvalid + CHUNK - 1) >> 8;  // non-empty chunks for this b

    const float* q    = wsin + (size_t)b * DM + h * DH;
    const float* knew = wsin + (size_t)NB_B * DM + (size_t)b * DM + h * DH;
    const float* vnew = wsin + (size_t)2 * NB_B * DM + (size_t)b * DM + h * DH;

    float4 qv0 = ((const float4*)q)[gl * 2];
    float4 qv1 = ((const float4*)q)[gl * 2 + 1];
    int phys_new = bt[b * NBLK + (pos >> 7)];
    int off_new  = pos & (BSZ - 1);

    const float* mrow = mask + (size_t)bh * KVLEN;
    const int* btrow = bt + b * NBLK;
    const unsigned bh_base = (unsigned)bh * NBLK;

    float m = -1e30f, l = 0.f;
    float4 ctx0 = {0.f, 0.f, 0.f, 0.f};
    float4 ctx1 = {0.f, 0.f, 0.f, 0.f};

    int n = end - start;
    {
        int nfull = n >> 5;                 // 32 positions per block-iteration
        int jg = start + wave * 8 + g;
#pragma unroll 2
        for (int it = 0; it < nfull; ++it) {
            int j = jg + it * 32;
            int blk = j >> 7;
            int p = j & (BSZ - 1);
            int ph = btrow[blk];
            bool isnew = (ph == phys_new) && (p == off_new);
            unsigned coff = ((bh_base + (unsigned)ph) * BSZ + (unsigned)p) * DH;
            const float4* kp = (const float4*)(isnew ? knew : (kc + coff));
            const float4* vp = (const float4*)(isnew ? vnew : (vc + coff));
            float4 k0 = kp[gl * 2], k1 = kp[gl * 2 + 1];
            float4 v0 = vp[gl * 2], v1 = vp[gl * 2 + 1];
            float sd = qv0.x * k0.x + qv0.y * k0.y + qv0.z * k0.z + qv0.w * k0.w
                     + qv1.x * k1.x + qv1.y * k1.y + qv1.z * k1.z + qv1.w * k1.w;
            sd += __shfl_xor(sd, 1);
            sd += __shfl_xor(sd, 2);
            sd += __shfl_xor(sd, 4);
            float sc = sd + mrow[j];
            float newm = fmaxf(m, sc);
            float scale = __expf(m - newm);
            float pr = __expf(sc - newm);
            l = l * scale + pr;
            ctx0.x = ctx0.x * scale + pr * v0.x;
            ctx0.y = ctx0.y * scale + pr * v0.y;
            ctx0.z = ctx0.z * scale + pr * v0.z;
            ctx0.w = ctx0.w * scale + pr * v0.w;
            ctx1.x = ctx1.x * scale + pr * v1.x;
            ctx1.y = ctx1.y * scale + pr * v1.y;
            ctx1.z = ctx1.z * scale + pr * v1.z;
            ctx1.w = ctx1.w * scale + pr * v1.w;
            m = newm;
        }
        if (n & 31) {
            int j = jg + nfull * 32;
            bool valid = (j < end);
            float4 k0 = {0,0,0,0}, k1 = {0,0,0,0};
            float4 v0 = {0,0,0,0}, v1 = {0,0,0,0};
            float msk = 0.f;
            if (valid) {
                int blk = j >> 7;
                int p = j & (BSZ - 1);
                int ph = btrow[blk];
                bool isnew = (ph == phys_new) && (p == off_new);
                unsigned coff = ((bh_base + (unsigned)ph) * BSZ + (unsigned)p) * DH;
                const float4* kp = (const float4*)(isnew ? knew : (kc + coff));
                const float4* vp = (const float4*)(isnew ? vnew : (vc + coff));
                k0 = kp[gl * 2]; k1 = kp[gl * 2 + 1];
                v0 = vp[gl * 2]; v1 = vp[gl * 2 + 1];
                msk = mrow[j];
            }
            float sd = qv0.x * k0.x + qv0.y * k0.y + qv0.z * k0.z + qv0.w * k0.w
                     + qv1.x * k1.x + qv1.y * k1.y + qv1.z * k1.z + qv1.w * k1.w;
            sd += __shfl_xor(sd, 1);
            sd += __shfl_xor(sd, 2);
            sd += __shfl_xor(sd, 4);
            float sc = valid ? (sd + msk) : -1e30f;
            float newm = fmaxf(m, sc);
            float scale = __expf(m - newm);
            float pr = valid ? __expf(sc - newm) : 0.f;
            l = l * scale + pr;
            ctx0.x = ctx0.x * scale + pr * v0.x;
            ctx0.y = ctx0.y * scale + pr * v0.y;
            ctx0.z = ctx0.z * scale + pr * v0.z;
            ctx0.w = ctx0.w * scale + pr * v0.w;
            ctx1.x = ctx1.x * scale + pr * v1.x;
            ctx1.y = ctx1.y * scale + pr * v1.y;
            ctx1.z = ctx1.z * scale + pr * v1.z;
            ctx1.w = ctx1.w * scale + pr * v1.w;
            m = newm;
        }
    }

    // combine 32 groups (4 waves x 8 groups); each group's ctx spans DH via
    // 8 lanes x 8 floats
    __shared__ float gm[32], glv[32];
    __shared__ float gctx[32][DH];
    int gid = wave * 8 + g;
    if (gl == 0) { gm[gid] = m; glv[gid] = l; }
    *((float4*)&gctx[gid][gl * 8])     = ctx0;
    *((float4*)&gctx[gid][gl * 8 + 4]) = ctx1;
    __syncthreads();

    size_t pi = (size_t)bh * NCH + c;
    if (tid < DH) {
        int d = tid;
        float M = -1e30f;
#pragma unroll
        for (int i = 0; i < 32; ++i) M = fmaxf(M, gm[i]);
        float L = 0.f, acc = 0.f;
#pragma unroll
        for (int i = 0; i < 32; ++i) {
            float w = __expf(gm[i] - M);
            L += w * glv[i];
            acc += w * gctx[i][d];
        }
        if (d == 0) { pm[pi] = M; pl[pi] = L; }
        pctx[pi * DH + d] = acc;
    }

    // ---- last-block-done reduce for this (b,h) ----
    __threadfence();                        // release partial writes
    __syncthreads();
    __shared__ int s_last;
    if (tid == 0) {
        int old = atomicAdd(&cnt[bh], 1);
        s_last = (old == nch_b - 1) ? 1 : 0;
    }
    __syncthreads();
    if (s_last) {
        __threadfence();                    // acquire other chunks' partials
        if (tid < DH) {
            int d = tid;
            float M = -1e30f;
            for (int ci = 0; ci < nch_b; ++ci)
                M = fmaxf(M, pm[(size_t)bh * NCH + ci]);
            float L = 0.f, acc = 0.f;
            for (int ci = 0; ci < nch_b; ++ci) {
                float w = __expf(pm[(size_t)bh * NCH + ci] - M);
                L += w * pl[(size_t)bh * NCH + ci];
                acc += w * pctx[((size_t)bh * NCH + ci) * DH + d];
            }
            ctx_out[(size_t)b * DM + h * DH + d] = acc / L;
        }
    }
}

extern "C" void kernel_launch(void* const* d_in, const int* in_sizes, int n_in,
                              void* d_out, int out_size, void* d_ws, size_t ws_size,
                              hipStream_t stream)
{
    const float* hs   = (const float*)d_in[0];
    const float* kc   = (const float*)d_in[1];
    const float* vc   = (const float*)d_in[2];
    const float* mask = (const float*)d_in[3];
    const int*   cpos = (const int*)d_in[4];
    const int*   bt   = (const int*)d_in[5];
    const float* Wq   = (const float*)d_in[6];
    const float* bq   = (const float*)d_in[7];
    const float* Wk   = (const float*)d_in[8];
    const float* bk   = (const float*)d_in[9];
    const float* Wv   = (const float*)d_in[10];
    const float* bv   = (const float*)d_in[11];
    const float* Wo   = (const float*)d_in[12];
    const float* bo   = (const float*)d_in[13];
    float* out = (float*)d_out;

    float* ws = (float*)d_ws;
    float* ws_qkv = ws;                                   // q,k_new,v_new: 3*B*DM
    float* pm   = ws + (size_t)3 * NB_B * DM;             // B*H*NCH
    float* pl   = pm + (size_t)NB_B * NH * NCH;           // B*H*NCH
    float* pctx = pl + (size_t)NB_B * NH * NCH;           // B*H*NCH*DH
    float* ctxf = pctx + (size_t)NB_B * NH * NCH * DH;    // B*DM
    int* cnt    = (int*)(ctxf + (size_t)NB_B * DM);       // B*H ints

    hipLaunchKernelGGL(qkv_all, dim3(3 * DM / 8), dim3(256), 0, stream,
                       hs, Wq, bq, Wk, bk, Wv, bv, ws_qkv, cnt);

    hipLaunchKernelGGL(attn_partial, dim3(NB_B * NH * NCH), dim3(256), 0, stream,
                       kc, vc, mask, cpos, bt, ws_qkv, pm, pl, pctx, ctxf, cnt);

    hipLaunchKernelGGL(out_all, dim3(DM / 4), dim3(128), 0, stream,
                       ctxf, Wo, bo, out);
}

// Round 9
// 62.837 us; speedup vs baseline: 8.1211x; 8.1211x over previous
//
#include <hip/hip_runtime.h>
#include <hip/hip_bf16.h>

#define NB_B 16
#define NH 16
#define NBLK 32
#define BSZ 128
#define DH 64
#define DM 1024
#define KVLEN 4096
#define NCH 16
#define CHUNK 256

// ws layout (floats):
// 0                  : q      (B*DM)
// B*DM               : k_new  (B*DM)
// 2*B*DM             : v_new  (B*DM)
// 3*B*DM             : part_m (B*H*NCH)
// +B*H*NCH           : part_l (B*H*NCH)
// +B*H*NCH           : part_ctx (B*H*NCH*DH)
// +B*H*NCH*DH        : ctx    (B*DM)

// One 32-lane group per weight row; full row (8 float4/lane) in registers;
// loop over all 16 batches staged in LDS. Weights stream from HBM once.
__global__ __launch_bounds__(256) void qkv_all(
    const float* __restrict__ hs,
    const float* __restrict__ Wq, const float* __restrict__ bq,
    const float* __restrict__ Wk, const float* __restrict__ bk,
    const float* __restrict__ Wv, const float* __restrict__ bv,
    float* __restrict__ ws)
{
    __shared__ float sh[NB_B][DM];          // 64 KB: all batches' hidden states
    int tid = threadIdx.x;
#pragma unroll
    for (int i = 0; i < 16; ++i) {
        int idx = i * 256 + tid;            // float4 index, 4096 total
        ((float4*)sh)[idx] = ((const float4*)hs)[idx];
    }
    __syncthreads();

    int grp = tid >> 5, gl = tid & 31;      // 8 groups of 32 lanes
    int row = blockIdx.x * 8 + grp;         // 0 .. 3*DM-1
    int m = row >> 10;                      // 0=q,1=k,2=v
    int o = row & (DM - 1);
    const float* W    = (m == 0) ? Wq : (m == 1) ? Wk : Wv;
    const float* bias = (m == 0) ? bq : (m == 1) ? bk : bv;
    const float4* wrow = (const float4*)(W + (size_t)o * DM);
    float4 w[8];
#pragma unroll
    for (int k = 0; k < 8; ++k) w[k] = wrow[gl + 32 * k];
    float bb = bias[o];

    for (int b = 0; b < NB_B; ++b) {
        const float4* x = (const float4*)sh[b];
        float acc = 0.f;
#pragma unroll
        for (int k = 0; k < 8; ++k) {
            float4 xv = x[gl + 32 * k];
            acc += w[k].x * xv.x + w[k].y * xv.y + w[k].z * xv.z + w[k].w * xv.w;
        }
        acc += __shfl_xor(acc, 1);
        acc += __shfl_xor(acc, 2);
        acc += __shfl_xor(acc, 4);
        acc += __shfl_xor(acc, 8);
        acc += __shfl_xor(acc, 16);
        if (gl == 0)
            ws[(size_t)m * (NB_B * DM) + (size_t)b * DM + o] = acc + bb;
    }
}

__global__ __launch_bounds__(128) void out_all(
    const float* __restrict__ ctx, const float* __restrict__ Wo,
    const float* __restrict__ bo, float* __restrict__ out)
{
    __shared__ float sh[NB_B][DM];          // 64 KB: all batches' context
    int tid = threadIdx.x;
#pragma unroll
    for (int i = 0; i < 32; ++i) {
        int idx = i * 128 + tid;
        ((float4*)sh)[idx] = ((const float4*)ctx)[idx];
    }
    __syncthreads();

    int grp = tid >> 5, gl = tid & 31;      // 4 groups of 32 lanes
    int o = blockIdx.x * 4 + grp;           // 0 .. DM-1
    const float4* wrow = (const float4*)(Wo + (size_t)o * DM);
    float4 w[8];
#pragma unroll
    for (int k = 0; k < 8; ++k) w[k] = wrow[gl + 32 * k];
    float bb = bo[o];

    for (int b = 0; b < NB_B; ++b) {
        const float4* x = (const float4*)sh[b];
        float acc = 0.f;
#pragma unroll
        for (int k = 0; k < 8; ++k) {
            float4 xv = x[gl + 32 * k];
            acc += w[k].x * xv.x + w[k].y * xv.y + w[k].z * xv.z + w[k].w * xv.w;
        }
        acc += __shfl_xor(acc, 1);
        acc += __shfl_xor(acc, 2);
        acc += __shfl_xor(acc, 4);
        acc += __shfl_xor(acc, 8);
        acc += __shfl_xor(acc, 16);
        if (gl == 0)
            out[(size_t)b * DM + o] = acc + bb;
    }
}

// 8-lane groups: each lane owns 8 contiguous floats of K/V; wave covers
// 8 positions per iteration. Balanced XCD mapping: id = c*256 + bh, so all
// 16 chunks of a (b,h) share id mod 8 -> same XCD (L2 reuse of duplicate
// physical blocks), while every XCD gets 2 heads of EVERY batch -> exactly
// balanced work across XCDs.
__global__ __launch_bounds__(256) void attn_partial(
    const float* __restrict__ kc, const float* __restrict__ vc,
    const float* __restrict__ mask,
    const int* __restrict__ cpos, const int* __restrict__ bt,
    const float* __restrict__ wsin,   // q, k_new, v_new
    float* __restrict__ pm, float* __restrict__ pl, float* __restrict__ pctx)
{
    int id = blockIdx.x;                    // 0..4095
    int c  = id >> 8;                       // 0..15
    int bh = id & 255;
    int b  = bh >> 4;
    int h  = bh & (NH - 1);

    int tid = threadIdx.x;
    int wave = tid >> 6, lane = tid & 63;
    int g = lane >> 3, gl = lane & 7;       // 8 groups of 8 lanes per wave

    int pos = cpos[b];
    int nvalid = pos + 1;
    int start = c * CHUNK;
    int end = min(start + CHUNK, nvalid);

    const float* q    = wsin + (size_t)b * DM + h * DH;
    const float* knew = wsin + (size_t)NB_B * DM + (size_t)b * DM + h * DH;
    const float* vnew = wsin + (size_t)2 * NB_B * DM + (size_t)b * DM + h * DH;

    float4 qv0 = ((const float4*)q)[gl * 2];
    float4 qv1 = ((const float4*)q)[gl * 2 + 1];
    int phys_new = bt[b * NBLK + (pos >> 7)];
    int off_new  = pos & (BSZ - 1);

    const float* mrow = mask + (size_t)bh * KVLEN;
    const int* btrow = bt + b * NBLK;
    const unsigned bh_base = (unsigned)bh * NBLK;

    float m = -1e30f, l = 0.f;
    float4 ctx0 = {0.f, 0.f, 0.f, 0.f};
    float4 ctx1 = {0.f, 0.f, 0.f, 0.f};

    int n = end - start;
    if (n > 0) {
        int nfull = n >> 5;                 // 32 positions per block-iteration
        int jg = start + wave * 8 + g;
#pragma unroll 2
        for (int it = 0; it < nfull; ++it) {
            int j = jg + it * 32;
            int blk = j >> 7;
            int p = j & (BSZ - 1);
            int ph = btrow[blk];
            bool isnew = (ph == phys_new) && (p == off_new);
            unsigned coff = ((bh_base + (unsigned)ph) * BSZ + (unsigned)p) * DH;
            const float4* kp = (const float4*)(isnew ? knew : (kc + coff));
            const float4* vp = (const float4*)(isnew ? vnew : (vc + coff));
            float4 k0 = kp[gl * 2], k1 = kp[gl * 2 + 1];
            float4 v0 = vp[gl * 2], v1 = vp[gl * 2 + 1];
            float sd = qv0.x * k0.x + qv0.y * k0.y + qv0.z * k0.z + qv0.w * k0.w
                     + qv1.x * k1.x + qv1.y * k1.y + qv1.z * k1.z + qv1.w * k1.w;
            sd += __shfl_xor(sd, 1);
            sd += __shfl_xor(sd, 2);
            sd += __shfl_xor(sd, 4);
            float sc = sd + mrow[j];
            float newm = fmaxf(m, sc);
            float scale = __expf(m - newm);
            float pr = __expf(sc - newm);
            l = l * scale + pr;
            ctx0.x = ctx0.x * scale + pr * v0.x;
            ctx0.y = ctx0.y * scale + pr * v0.y;
            ctx0.z = ctx0.z * scale + pr * v0.z;
            ctx0.w = ctx0.w * scale + pr * v0.w;
            ctx1.x = ctx1.x * scale + pr * v1.x;
            ctx1.y = ctx1.y * scale + pr * v1.y;
            ctx1.z = ctx1.z * scale + pr * v1.z;
            ctx1.w = ctx1.w * scale + pr * v1.w;
            m = newm;
        }
        if (n & 31) {
            int j = jg + nfull * 32;
            bool valid = (j < end);
            float4 k0 = {0,0,0,0}, k1 = {0,0,0,0};
            float4 v0 = {0,0,0,0}, v1 = {0,0,0,0};
            float msk = 0.f;
            if (valid) {
                int blk = j >> 7;
                int p = j & (BSZ - 1);
                int ph = btrow[blk];
                bool isnew = (ph == phys_new) && (p == off_new);
                unsigned coff = ((bh_base + (unsigned)ph) * BSZ + (unsigned)p) * DH;
                const float4* kp = (const float4*)(isnew ? knew : (kc + coff));
                const float4* vp = (const float4*)(isnew ? vnew : (vc + coff));
                k0 = kp[gl * 2]; k1 = kp[gl * 2 + 1];
                v0 = vp[gl * 2]; v1 = vp[gl * 2 + 1];
                msk = mrow[j];
            }
            float sd = qv0.x * k0.x + qv0.y * k0.y + qv0.z * k0.z + qv0.w * k0.w
                     + qv1.x * k1.x + qv1.y * k1.y + qv1.z * k1.z + qv1.w * k1.w;
            sd += __shfl_xor(sd, 1);
            sd += __shfl_xor(sd, 2);
            sd += __shfl_xor(sd, 4);
            float sc = valid ? (sd + msk) : -1e30f;
            float newm = fmaxf(m, sc);
            float scale = __expf(m - newm);
            float pr = valid ? __expf(sc - newm) : 0.f;
            l = l * scale + pr;
            ctx0.x = ctx0.x * scale + pr * v0.x;
            ctx0.y = ctx0.y * scale + pr * v0.y;
            ctx0.z = ctx0.z * scale + pr * v0.z;
            ctx0.w = ctx0.w * scale + pr * v0.w;
            ctx1.x = ctx1.x * scale + pr * v1.x;
            ctx1.y = ctx1.y * scale + pr * v1.y;
            ctx1.z = ctx1.z * scale + pr * v1.z;
            ctx1.w = ctx1.w * scale + pr * v1.w;
            m = newm;
        }
    }

    // combine 32 groups (4 waves x 8 groups); each group's ctx spans DH via
    // 8 lanes x 8 floats
    __shared__ float gm[32], glv[32];
    __shared__ float gctx[32][DH];
    int gid = wave * 8 + g;
    if (gl == 0) { gm[gid] = m; glv[gid] = l; }
    *((float4*)&gctx[gid][gl * 8])     = ctx0;
    *((float4*)&gctx[gid][gl * 8 + 4]) = ctx1;
    __syncthreads();

    if (tid < DH) {
        int d = tid;
        float M = -1e30f;
#pragma unroll
        for (int i = 0; i < 32; ++i) M = fmaxf(M, gm[i]);
        float L = 0.f, acc = 0.f;
#pragma unroll
        for (int i = 0; i < 32; ++i) {
            float w = __expf(gm[i] - M);
            L += w * glv[i];
            acc += w * gctx[i][d];
        }
        size_t pi = (size_t)bh * NCH + c;
        if (d == 0) { pm[pi] = M; pl[pi] = L; }
        pctx[pi * DH + d] = acc;
    }
}

__global__ __launch_bounds__(64) void attn_reduce(
    const float* __restrict__ pm, const float* __restrict__ pl,
    const float* __restrict__ pctx, float* __restrict__ ctx_out)
{
    int bh = blockIdx.x;       // b*H + h
    int d = threadIdx.x;       // 0..63
    float M = -1e30f;
#pragma unroll
    for (int ci = 0; ci < NCH; ++ci) M = fmaxf(M, pm[(size_t)bh * NCH + ci]);
    float L = 0.f, acc = 0.f;
#pragma unroll
    for (int ci = 0; ci < NCH; ++ci) {
        float w = __expf(pm[(size_t)bh * NCH + ci] - M);
        L += w * pl[(size_t)bh * NCH + ci];
        acc += w * pctx[((size_t)bh * NCH + ci) * DH + d];
    }
    int b = bh / NH, h = bh % NH;
    ctx_out[(size_t)b * DM + h * DH + d] = acc / L;
}

extern "C" void kernel_launch(void* const* d_in, const int* in_sizes, int n_in,
                              void* d_out, int out_size, void* d_ws, size_t ws_size,
                              hipStream_t stream)
{
    const float* hs   = (const float*)d_in[0];
    const float* kc   = (const float*)d_in[1];
    const float* vc   = (const float*)d_in[2];
    const float* mask = (const float*)d_in[3];
    const int*   cpos = (const int*)d_in[4];
    const int*   bt   = (const int*)d_in[5];
    const float* Wq   = (const float*)d_in[6];
    const float* bq   = (const float*)d_in[7];
    const float* Wk   = (const float*)d_in[8];
    const float* bk   = (const float*)d_in[9];
    const float* Wv   = (const float*)d_in[10];
    const float* bv   = (const float*)d_in[11];
    const float* Wo   = (const float*)d_in[12];
    const float* bo   = (const float*)d_in[13];
    float* out = (float*)d_out;

    float* ws = (float*)d_ws;
    float* ws_qkv = ws;                                   // q,k_new,v_new: 3*B*DM
    float* pm   = ws + (size_t)3 * NB_B * DM;             // B*H*NCH
    float* pl   = pm + (size_t)NB_B * NH * NCH;           // B*H*NCH
    float* pctx = pl + (size_t)NB_B * NH * NCH;           // B*H*NCH*DH
    float* ctxf = pctx + (size_t)NB_B * NH * NCH * DH;    // B*DM

    hipLaunchKernelGGL(qkv_all, dim3(3 * DM / 8), dim3(256), 0, stream,
                       hs, Wq, bq, Wk, bk, Wv, bv, ws_qkv);

    hipLaunchKernelGGL(attn_partial, dim3(NB_B * NH * NCH), dim3(256), 0, stream,
                       kc, vc, mask, cpos, bt, ws_qkv, pm, pl, pctx);

    hipLaunchKernelGGL(attn_reduce, dim3(NB_B * NH), dim3(64), 0, stream,
                       pm, pl, pctx, ctxf);

    hipLaunchKernelGGL(out_all, dim3(DM / 4), dim3(128), 0, stream,
                       ctxf, Wo, bo, out);
}

// Round 10
// 61.750 us; speedup vs baseline: 8.2639x; 1.0176x over previous
//
#include <hip/hip_runtime.h>
#include <hip/hip_bf16.h>

#define NB_B 16
#define NH 16
#define NBLK 32
#define BSZ 128
#define DH 64
#define DM 1024
#define KVLEN 4096
#define NCH 8
#define CHUNK 512

// ws layout (floats):
// 0                  : q      (B*DM)
// B*DM               : k_new  (B*DM)
// 2*B*DM             : v_new  (B*DM)
// 3*B*DM             : part_m (B*H*NCH)
// +B*H*NCH           : part_l (B*H*NCH)
// +B*H*NCH           : part_ctx (B*H*NCH*DH)
// +B*H*NCH*DH        : ctx    (B*DM)

// One 32-lane group per weight row; full row (8 float4/lane) in registers;
// loop over all 16 batches staged in LDS. Weights stream from HBM once.
__global__ __launch_bounds__(256) void qkv_all(
    const float* __restrict__ hs,
    const float* __restrict__ Wq, const float* __restrict__ bq,
    const float* __restrict__ Wk, const float* __restrict__ bk,
    const float* __restrict__ Wv, const float* __restrict__ bv,
    float* __restrict__ ws)
{
    __shared__ float sh[NB_B][DM];          // 64 KB: all batches' hidden states
    int tid = threadIdx.x;
#pragma unroll
    for (int i = 0; i < 16; ++i) {
        int idx = i * 256 + tid;            // float4 index, 4096 total
        ((float4*)sh)[idx] = ((const float4*)hs)[idx];
    }
    __syncthreads();

    int grp = tid >> 5, gl = tid & 31;      // 8 groups of 32 lanes
    int row = blockIdx.x * 8 + grp;         // 0 .. 3*DM-1
    int m = row >> 10;                      // 0=q,1=k,2=v
    int o = row & (DM - 1);
    const float* W    = (m == 0) ? Wq : (m == 1) ? Wk : Wv;
    const float* bias = (m == 0) ? bq : (m == 1) ? bk : bv;
    const float4* wrow = (const float4*)(W + (size_t)o * DM);
    float4 w[8];
#pragma unroll
    for (int k = 0; k < 8; ++k) w[k] = wrow[gl + 32 * k];
    float bb = bias[o];

    for (int b = 0; b < NB_B; ++b) {
        const float4* x = (const float4*)sh[b];
        float acc = 0.f;
#pragma unroll
        for (int k = 0; k < 8; ++k) {
            float4 xv = x[gl + 32 * k];
            acc += w[k].x * xv.x + w[k].y * xv.y + w[k].z * xv.z + w[k].w * xv.w;
        }
        acc += __shfl_xor(acc, 1);
        acc += __shfl_xor(acc, 2);
        acc += __shfl_xor(acc, 4);
        acc += __shfl_xor(acc, 8);
        acc += __shfl_xor(acc, 16);
        if (gl == 0)
            ws[(size_t)m * (NB_B * DM) + (size_t)b * DM + o] = acc + bb;
    }
}

__global__ __launch_bounds__(128) void out_all(
    const float* __restrict__ ctx, const float* __restrict__ Wo,
    const float* __restrict__ bo, float* __restrict__ out)
{
    __shared__ float sh[NB_B][DM];          // 64 KB: all batches' context
    int tid = threadIdx.x;
#pragma unroll
    for (int i = 0; i < 32; ++i) {
        int idx = i * 128 + tid;
        ((float4*)sh)[idx] = ((const float4*)ctx)[idx];
    }
    __syncthreads();

    int grp = tid >> 5, gl = tid & 31;      // 4 groups of 32 lanes
    int o = blockIdx.x * 4 + grp;           // 0 .. DM-1
    const float4* wrow = (const float4*)(Wo + (size_t)o * DM);
    float4 w[8];
#pragma unroll
    for (int k = 0; k < 8; ++k) w[k] = wrow[gl + 32 * k];
    float bb = bo[o];

    for (int b = 0; b < NB_B; ++b) {
        const float4* x = (const float4*)sh[b];
        float acc = 0.f;
#pragma unroll
        for (int k = 0; k < 8; ++k) {
            float4 xv = x[gl + 32 * k];
            acc += w[k].x * xv.x + w[k].y * xv.y + w[k].z * xv.z + w[k].w * xv.w;
        }
        acc += __shfl_xor(acc, 1);
        acc += __shfl_xor(acc, 2);
        acc += __shfl_xor(acc, 4);
        acc += __shfl_xor(acc, 8);
        acc += __shfl_xor(acc, 16);
        if (gl == 0)
            out[(size_t)b * DM + o] = acc + bb;
    }
}

// 8-lane groups: each lane owns 8 contiguous floats of K/V; wave covers
// 8 positions per iteration. Balanced XCD mapping: id = c*256 + bh, so all
// 8 chunks of a (b,h) share id mod 8 -> same XCD (L2 reuse of duplicate
// physical blocks), while every XCD gets 2 heads of EVERY batch -> exactly
// balanced work across XCDs. CHUNK=512 halves per-block fixed overhead.
__global__ __launch_bounds__(256) void attn_partial(
    const float* __restrict__ kc, const float* __restrict__ vc,
    const float* __restrict__ mask,
    const int* __restrict__ cpos, const int* __restrict__ bt,
    const float* __restrict__ wsin,   // q, k_new, v_new
    float* __restrict__ pm, float* __restrict__ pl, float* __restrict__ pctx)
{
    int id = blockIdx.x;                    // 0..2047
    int c  = id >> 8;                       // 0..7
    int bh = id & 255;
    int b  = bh >> 4;
    int h  = bh & (NH - 1);

    int tid = threadIdx.x;
    int wave = tid >> 6, lane = tid & 63;
    int g = lane >> 3, gl = lane & 7;       // 8 groups of 8 lanes per wave

    int pos = cpos[b];
    int nvalid = pos + 1;
    int start = c * CHUNK;
    int end = min(start + CHUNK, nvalid);

    const float* q    = wsin + (size_t)b * DM + h * DH;
    const float* knew = wsin + (size_t)NB_B * DM + (size_t)b * DM + h * DH;
    const float* vnew = wsin + (size_t)2 * NB_B * DM + (size_t)b * DM + h * DH;

    float4 qv0 = ((const float4*)q)[gl * 2];
    float4 qv1 = ((const float4*)q)[gl * 2 + 1];
    int phys_new = bt[b * NBLK + (pos >> 7)];
    int off_new  = pos & (BSZ - 1);

    const float* mrow = mask + (size_t)bh * KVLEN;
    const int* btrow = bt + b * NBLK;
    const unsigned bh_base = (unsigned)bh * NBLK;

    float m = -1e30f, l = 0.f;
    float4 ctx0 = {0.f, 0.f, 0.f, 0.f};
    float4 ctx1 = {0.f, 0.f, 0.f, 0.f};

    int n = end - start;
    if (n > 0) {
        int nfull = n >> 5;                 // 32 positions per block-iteration
        int jg = start + wave * 8 + g;
#pragma unroll 2
        for (int it = 0; it < nfull; ++it) {
            int j = jg + it * 32;
            int blk = j >> 7;
            int p = j & (BSZ - 1);
            int ph = btrow[blk];
            bool isnew = (ph == phys_new) && (p == off_new);
            unsigned coff = ((bh_base + (unsigned)ph) * BSZ + (unsigned)p) * DH;
            const float4* kp = (const float4*)(isnew ? knew : (kc + coff));
            const float4* vp = (const float4*)(isnew ? vnew : (vc + coff));
            float4 k0 = kp[gl * 2], k1 = kp[gl * 2 + 1];
            float4 v0 = vp[gl * 2], v1 = vp[gl * 2 + 1];
            float sd = qv0.x * k0.x + qv0.y * k0.y + qv0.z * k0.z + qv0.w * k0.w
                     + qv1.x * k1.x + qv1.y * k1.y + qv1.z * k1.z + qv1.w * k1.w;
            sd += __shfl_xor(sd, 1);
            sd += __shfl_xor(sd, 2);
            sd += __shfl_xor(sd, 4);
            float sc = sd + mrow[j];
            float newm = fmaxf(m, sc);
            float scale = __expf(m - newm);
            float pr = __expf(sc - newm);
            l = l * scale + pr;
            ctx0.x = ctx0.x * scale + pr * v0.x;
            ctx0.y = ctx0.y * scale + pr * v0.y;
            ctx0.z = ctx0.z * scale + pr * v0.z;
            ctx0.w = ctx0.w * scale + pr * v0.w;
            ctx1.x = ctx1.x * scale + pr * v1.x;
            ctx1.y = ctx1.y * scale + pr * v1.y;
            ctx1.z = ctx1.z * scale + pr * v1.z;
            ctx1.w = ctx1.w * scale + pr * v1.w;
            m = newm;
        }
        if (n & 31) {
            int j = jg + nfull * 32;
            bool valid = (j < end);
            float4 k0 = {0,0,0,0}, k1 = {0,0,0,0};
            float4 v0 = {0,0,0,0}, v1 = {0,0,0,0};
            float msk = 0.f;
            if (valid) {
                int blk = j >> 7;
                int p = j & (BSZ - 1);
                int ph = btrow[blk];
                bool isnew = (ph == phys_new) && (p == off_new);
                unsigned coff = ((bh_base + (unsigned)ph) * BSZ + (unsigned)p) * DH;
                const float4* kp = (const float4*)(isnew ? knew : (kc + coff));
                const float4* vp = (const float4*)(isnew ? vnew : (vc + coff));
                k0 = kp[gl * 2]; k1 = kp[gl * 2 + 1];
                v0 = vp[gl * 2]; v1 = vp[gl * 2 + 1];
                msk = mrow[j];
            }
            float sd = qv0.x * k0.x + qv0.y * k0.y + qv0.z * k0.z + qv0.w * k0.w
                     + qv1.x * k1.x + qv1.y * k1.y + qv1.z * k1.z + qv1.w * k1.w;
            sd += __shfl_xor(sd, 1);
            sd += __shfl_xor(sd, 2);
            sd += __shfl_xor(sd, 4);
            float sc = valid ? (sd + msk) : -1e30f;
            float newm = fmaxf(m, sc);
            float scale = __expf(m - newm);
            float pr = valid ? __expf(sc - newm) : 0.f;
            l = l * scale + pr;
            ctx0.x = ctx0.x * scale + pr * v0.x;
            ctx0.y = ctx0.y * scale + pr * v0.y;
            ctx0.z = ctx0.z * scale + pr * v0.z;
            ctx0.w = ctx0.w * scale + pr * v0.w;
            ctx1.x = ctx1.x * scale + pr * v1.x;
            ctx1.y = ctx1.y * scale + pr * v1.y;
            ctx1.z = ctx1.z * scale + pr * v1.z;
            ctx1.w = ctx1.w * scale + pr * v1.w;
            m = newm;
        }
    }

    // combine 32 groups (4 waves x 8 groups); each group's ctx spans DH via
    // 8 lanes x 8 floats
    __shared__ float gm[32], glv[32];
    __shared__ float gctx[32][DH];
    int gid = wave * 8 + g;
    if (gl == 0) { gm[gid] = m; glv[gid] = l; }
    *((float4*)&gctx[gid][gl * 8])     = ctx0;
    *((float4*)&gctx[gid][gl * 8 + 4]) = ctx1;
    __syncthreads();

    if (tid < DH) {
        int d = tid;
        float M = -1e30f;
#pragma unroll
        for (int i = 0; i < 32; ++i) M = fmaxf(M, gm[i]);
        float L = 0.f, acc = 0.f;
#pragma unroll
        for (int i = 0; i < 32; ++i) {
            float w = __expf(gm[i] - M);
            L += w * glv[i];
            acc += w * gctx[i][d];
        }
        size_t pi = (size_t)bh * NCH + c;
        if (d == 0) { pm[pi] = M; pl[pi] = L; }
        pctx[pi * DH + d] = acc;
    }
}

__global__ __launch_bounds__(64) void attn_reduce(
    const float* __restrict__ pm, const float* __restrict__ pl,
    const float* __restrict__ pctx, float* __restrict__ ctx_out)
{
    int bh = blockIdx.x;       // b*H + h
    int d = threadIdx.x;       // 0..63
    float M = -1e30f;
#pragma unroll
    for (int ci = 0; ci < NCH; ++ci) M = fmaxf(M, pm[(size_t)bh * NCH + ci]);
    float L = 0.f, acc = 0.f;
#pragma unroll
    for (int ci = 0; ci < NCH; ++ci) {
        float w = __expf(pm[(size_t)bh * NCH + ci] - M);
        L += w * pl[(size_t)bh * NCH + ci];
        acc += w * pctx[((size_t)bh * NCH + ci) * DH + d];
    }
    int b = bh / NH, h = bh % NH;
    ctx_out[(size_t)b * DM + h * DH + d] = acc / L;
}

extern "C" void kernel_launch(void* const* d_in, const int* in_sizes, int n_in,
                              void* d_out, int out_size, void* d_ws, size_t ws_size,
                              hipStream_t stream)
{
    const float* hs   = (const float*)d_in[0];
    const float* kc   = (const float*)d_in[1];
    const float* vc   = (const float*)d_in[2];
    const float* mask = (const float*)d_in[3];
    const int*   cpos = (const int*)d_in[4];
    const int*   bt   = (const int*)d_in[5];
    const float* Wq   = (const float*)d_in[6];
    const float* bq   = (const float*)d_in[7];
    const float* Wk   = (const float*)d_in[8];
    const float* bk   = (const float*)d_in[9];
    const float* Wv   = (const float*)d_in[10];
    const float* bv   = (const float*)d_in[11];
    const float* Wo   = (const float*)d_in[12];
    const float* bo   = (const float*)d_in[13];
    float* out = (float*)d_out;

    float* ws = (float*)d_ws;
    float* ws_qkv = ws;                                   // q,k_new,v_new: 3*B*DM
    float* pm   = ws + (size_t)3 * NB_B * DM;             // B*H*NCH
    float* pl   = pm + (size_t)NB_B * NH * NCH;           // B*H*NCH
    float* pctx = pl + (size_t)NB_B * NH * NCH;           // B*H*NCH*DH
    float* ctxf = pctx + (size_t)NB_B * NH * NCH * DH;    // B*DM

    hipLaunchKernelGGL(qkv_all, dim3(3 * DM / 8), dim3(256), 0, stream,
                       hs, Wq, bq, Wk, bk, Wv, bv, ws_qkv);

    hipLaunchKernelGGL(attn_partial, dim3(NB_B * NH * NCH), dim3(256), 0, stream,
                       kc, vc, mask, cpos, bt, ws_qkv, pm, pl, pctx);

    hipLaunchKernelGGL(attn_reduce, dim3(NB_B * NH), dim3(64), 0, stream,
                       pm, pl, pctx, ctxf);

    hipLaunchKernelGGL(out_all, dim3(DM / 4), dim3(128), 0, stream,
                       ctxf, Wo, bo, out);
}